// Round 16
// baseline (253.996 us; speedup 1.0000x reference)
//
#include <hip/hip_runtime.h>

// DiscreteMMSE, round 16 (= r15 resubmit; r15 was an infra failure with no
// signal — same error mode that passed identical code in r1->r2).
// Producer/consumer wave specialization.
//
//   data   : [B=128][N=128][D=64] f32
//   targets: [B=128][N=128]       f32
//   W      : [D=64][T=4096]       f32
//   out    : [B=128][N=128]       f32
//
// r14 post-mortem: exp-lowering theory dead (native __expf: 215us = r6's
// 210 = r10's 228). Three different softmax implementations all ~215us at
// VALUBusy ~53%, 2 waves/SIMD => softmax is LATENCY-bound and waves run in
// phase lockstep (all GEMM together, all softmax together; nothing fills
// the softmax stalls).
//
// Fix: per (b,chunk), 128-thread block = {wave0: producer, wave1: consumer}.
// Producer GEMMs an NT=8-row mu tile (2048 FMA, pure VALU) into LDS
// buf[k&1]; consumer runs the 8 softmax steps of tile k-1 from buf[(k-1)&1].
// ONE uniform __syncthreads per tile. Dbuf correctness: consumer's read of
// buf[x] in iter k finishes before the barrier ending iter k; producer's
// next write of buf[x] is in iter k+1 (x=(k+1)&1) -- always >=1 barrier
// apart. Consumer latency chains now overlap producer FMAs BY CONSTRUCTION.
// 4096 waves = 4/SIMD; LDS 16KB/block.
//
// Numerics identical to r14 (ln-units csum, __expf, per-16-lane-group Mg
// reference via DPP max tree, DPP group sums, associative wave combine,
// (m,s,p) partials to 4MB ws, K2 online combine). Proven: r6/r10/r14.

#define B 128
#define N 128
#define D 64
#define T 4096
#define NT 8
#define NTILES (N / NT)      // 16
#define NCHUNK 16
#define K1_GRID (B * NCHUNK) // 2048 blocks, 128 threads each

// DPP ctrl codes
#define DPP_XOR1 0xB1    // quad_perm(1,0,3,2)
#define DPP_XOR2 0x4E    // quad_perm(2,3,0,1)
#define DPP_XOR4 0x141   // row_half_mirror
#define DPP_XOR8 0x140   // row_mirror

template <int CTRL>
__device__ __forceinline__ float dppf(float x) {
    return __int_as_float(
        __builtin_amdgcn_mov_dpp(__float_as_int(x), CTRL, 0xF, 0xF, true));
}

// 16-lane-group max tree (all lanes of the group get the result). VALU-only.
__device__ __forceinline__ float dpp_max16(float m) {
    m = fmaxf(m, dppf<DPP_XOR1>(m));
    m = fmaxf(m, dppf<DPP_XOR2>(m));
    m = fmaxf(m, dppf<DPP_XOR4>(m));
    m = fmaxf(m, dppf<DPP_XOR8>(m));
    return m;
}

// 16-lane-group sum tree. VALU-only.
__device__ __forceinline__ float dpp_sum16(float s) {
    s += dppf<DPP_XOR1>(s);
    s += dppf<DPP_XOR2>(s);
    s += dppf<DPP_XOR4>(s);
    s += dppf<DPP_XOR8>(s);
    return s;
}

__global__ __launch_bounds__(128, 2)
void dmmse_k1(const float* __restrict__ data,
              const float* __restrict__ targets,
              const float* __restrict__ W,
              float4* __restrict__ part)      // [NCHUNK][B*N] (m, s, p, _)
{
    const int tid   = threadIdx.x;
    const int lane  = tid & 63;
    const int wid   = tid >> 6;               // 0 = producer, 1 = consumer
    const int b     = blockIdx.x >> 4;
    const int chunk = blockIdx.x & 15;

    __shared__ float muf[2][NT][256];         // 16 KB, double-buffered mu tile

    const float4* W4   = reinterpret_cast<const float4*>(W);  // [D][T/4]
    const int     wcol = chunk * 64 + lane;                   // float4 col index

    // consumer state (ln-units csum; Mg = per-16-lane-group max of csum_{n-1})
    float csum0 = 0.f, csum1 = 0.f, csum2 = 0.f, csum3 = 0.f;
    float Mg = 0.f;

    for (int k = 0; k <= NTILES; ++k) {
        if (wid == 0 && k < NTILES) {
            // ---------------- producer: GEMM tile k -> LDS buf[k&1] --------
            float mu[NT][4];
            #pragma unroll
            for (int i = 0; i < NT; ++i) { mu[i][0]=0.f; mu[i][1]=0.f; mu[i][2]=0.f; mu[i][3]=0.f; }

            const float* drow = data + (b * N + k * NT) * D;   // lane-uniform

#define FMA_GROUP(dc_, wv0, wv1, wv2, wv3)                                     \
            _Pragma("unroll")                                                  \
            for (int i = 0; i < NT; ++i) {                                     \
                const float4 x = *reinterpret_cast<const float4*>(drow + i * D + (dc_)); \
                mu[i][0] = fmaf(x.x, wv0.x, mu[i][0]);                         \
                mu[i][1] = fmaf(x.x, wv0.y, mu[i][1]);                         \
                mu[i][2] = fmaf(x.x, wv0.z, mu[i][2]);                         \
                mu[i][3] = fmaf(x.x, wv0.w, mu[i][3]);                         \
                mu[i][0] = fmaf(x.y, wv1.x, mu[i][0]);                         \
                mu[i][1] = fmaf(x.y, wv1.y, mu[i][1]);                         \
                mu[i][2] = fmaf(x.y, wv1.z, mu[i][2]);                         \
                mu[i][3] = fmaf(x.y, wv1.w, mu[i][3]);                         \
                mu[i][0] = fmaf(x.z, wv2.x, mu[i][0]);                         \
                mu[i][1] = fmaf(x.z, wv2.y, mu[i][1]);                         \
                mu[i][2] = fmaf(x.z, wv2.z, mu[i][2]);                         \
                mu[i][3] = fmaf(x.z, wv2.w, mu[i][3]);                         \
                mu[i][0] = fmaf(x.w, wv3.x, mu[i][0]);                         \
                mu[i][1] = fmaf(x.w, wv3.y, mu[i][1]);                         \
                mu[i][2] = fmaf(x.w, wv3.z, mu[i][2]);                         \
                mu[i][3] = fmaf(x.w, wv3.w, mu[i][3]);                         \
            }

            float4 a0 = W4[0 * (T / 4) + wcol];
            float4 a1 = W4[1 * (T / 4) + wcol];
            float4 a2 = W4[2 * (T / 4) + wcol];
            float4 a3 = W4[3 * (T / 4) + wcol];
            for (int dc = 0; dc < D - 4; dc += 4) {
                const float4 b0 = W4[(dc + 4) * (T / 4) + wcol];
                const float4 b1 = W4[(dc + 5) * (T / 4) + wcol];
                const float4 b2 = W4[(dc + 6) * (T / 4) + wcol];
                const float4 b3 = W4[(dc + 7) * (T / 4) + wcol];
                FMA_GROUP(dc, a0, a1, a2, a3)
                a0 = b0; a1 = b1; a2 = b2; a3 = b3;
            }
            FMA_GROUP(D - 4, a0, a1, a2, a3)
#undef FMA_GROUP

            #pragma unroll
            for (int i = 0; i < NT; ++i)
                *reinterpret_cast<float4*>(&muf[k & 1][i][lane << 2]) =
                    make_float4(mu[i][0], mu[i][1], mu[i][2], mu[i][3]);
        }

        if (wid == 1 && k >= 1) {
            // ---------------- consumer: softmax steps of tile k-1 ----------
            const int t = k - 1;
            #pragma unroll
            for (int i = 0; i < NT; ++i) {
                const int n = t * NT + i;

                const float4 mu4 =
                    *reinterpret_cast<const float4*>(&muf[t & 1][i][lane << 2]);

                // weights vs csum_{n-1}, group-local reference Mg (exact max)
                const float e0 = __expf(csum0 - Mg);
                const float e1 = __expf(csum1 - Mg);
                const float e2 = __expf(csum2 - Mg);
                const float e3 = __expf(csum3 - Mg);
                float s = (e0 + e1) + (e2 + e3);
                float p = fmaf(e0, mu4.x,
                          fmaf(e1, mu4.y,
                          fmaf(e2, mu4.z, e3 * mu4.w)));

                // group sums (off the step-to-step chain)
                s = dpp_sum16(s);
                p = dpp_sum16(p);

                // associative wave combine of the 4 group triples (off-chain)
                float mw = Mg, sw = s, pw = p;
                {
                    const float mx = __shfl_xor(mw, 16, 64);
                    const float sx = __shfl_xor(sw, 16, 64);
                    const float px = __shfl_xor(pw, 16, 64);
                    const float mn = fmaxf(mw, mx);
                    const float fa = __expf(mw - mn);
                    const float fb = __expf(mx - mn);
                    sw = fmaf(sw, fa, sx * fb);
                    pw = fmaf(pw, fa, px * fb);
                    mw = mn;
                }
                {
                    const float mx = __shfl_xor(mw, 32, 64);
                    const float sx = __shfl_xor(sw, 32, 64);
                    const float px = __shfl_xor(pw, 32, 64);
                    const float mn = fmaxf(mw, mx);
                    const float fa = __expf(mw - mn);
                    const float fb = __expf(mx - mn);
                    sw = fmaf(sw, fa, sx * fb);
                    pw = fmaf(pw, fa, px * fb);
                    mw = mn;
                }
                if (lane == 0)
                    part[chunk * (B * N) + b * N + n] = make_float4(mw, sw, pw, 0.f);

                // csum update; Mg tree is the only serial carry to step n+1
                if (n < N - 1) {
                    const float y = targets[b * N + n];   // lane-uniform
                    float e;
                    e = y - mu4.x; csum0 = fmaf(-0.5f * e, e, csum0);
                    e = y - mu4.y; csum1 = fmaf(-0.5f * e, e, csum1);
                    e = y - mu4.z; csum2 = fmaf(-0.5f * e, e, csum2);
                    e = y - mu4.w; csum3 = fmaf(-0.5f * e, e, csum3);
                }
                Mg = dpp_max16(fmaxf(fmaxf(csum0, csum1), fmaxf(csum2, csum3)));
            }
        }

        __syncthreads();   // uniform: ends tile period k
    }
}

__global__ __launch_bounds__(256)
void dmmse_k2(const float4* __restrict__ part,   // [NCHUNK][B*N]
              float* __restrict__ out)           // [B*N]
{
    const int t = blockIdx.x * 256 + threadIdx.x;

    // online associative softmax combine over chunk partials
    float M = -__builtin_inff(), S = 0.f, P = 0.f;
    #pragma unroll
    for (int c = 0; c < NCHUNK; ++c) {
        const float4 v = part[c * (B * N) + t];     // lane-coalesced
        const float nM = fmaxf(M, v.x);
        const float aa = __expf(M - nM);
        const float f  = __expf(v.x - nM);
        S = S * aa + v.y * f;
        P = P * aa + v.z * f;
        M = nM;
    }
    out[t] = P / S;
}

extern "C" void kernel_launch(void* const* d_in, const int* in_sizes, int n_in,
                              void* d_out, int out_size, void* d_ws, size_t ws_size,
                              hipStream_t stream)
{
    const float* data    = (const float*)d_in[0];   // 128*128*64
    const float* targets = (const float*)d_in[1];   // 128*128
    const float* W       = (const float*)d_in[2];   // 64*4096
    float* out           = (float*)d_out;           // 128*128
    float4* part         = (float4*)d_ws;           // 4 MB partials (proven)

    dmmse_k1<<<K1_GRID, 128, 0, stream>>>(data, targets, W, part);
    dmmse_k2<<<(B * N) / 256, 256, 0, stream>>>(part, out);
}